// Round 4
// baseline (784.311 us; speedup 1.0000x reference)
//
#include <hip/hip_runtime.h>
#include <hip/hip_bf16.h>

// LIF layer: lif_input[T,NOUT] = x[T,NIN] @ W[NOUT,NIN]^T (fp32), then sequential scan.
// fp32 GEMM on matrix pipe via fp16 2-way SCALED split, 3 MFMA products:
//   a = a0 + a1*2^-12 (a1 pre-scaled by 2^12: dodges fp16 subnormal flush)
//   C = acc0(A0B0) + 2^-12 * acc1(A0B1 + A1B0); error ~2^-24|ab| (fp32-noise level).
// Round-10 (GEMM only; splits + round-8 asm-ring scan kept):
//  - Round-9 post-mortem: 64x32 wave-tiles raised LDS read traffic to 512 B/MFMA
//    (cap ~61% MfmaUtil) AND 1 block/CU removed the cross-block barrier filler
//    that gave round 8 its 52%. Both reverted.
//  - Round-10 = round-8 geometry (128x128 tile, 4 waves of 64x64 = 341 B/MFMA,
//    256 thr, 2 blocks/CU, grid 512) + orthogonal pipeline: BK=32 double-buffered
//    LDS (2 x 32 KB = 64 KB -> still 2 blocks/CU), counted s_waitcnt vmcnt(8)
//    (own prior-tile GLLs: exactly 8 younger ops) + raw s_barrier (no vmcnt(0)
//    drain). Prefetch window = one compute phase (~466 cy wall) covers L2-hit
//    latency (~200-400 cy; ~88% of LDS-feed traffic is L2-hit per FETCH_SIZE);
//    2-block overlap fills barriers + residual HBM-miss stalls.
//  - BK=32 bank layout: row r (64 B) stored paired: halves_off(r, slot) =
//    (r>>1)*64 + (r&1)*32 + (slot ^ ((r>>1)&3))*8. A 16-lane quad-group's
//    ds_read_b128 then touches 8 distinct bank-quads (2-way alias only = free).
//    GLL lane mapping (linear dest lane*16B): row = 2*(lane>>3) + ((lane>>2)&1),
//    stored slot = lane&3, true k-group = (lane&3) ^ ((lane>>3)&3) -> applied to
//    the per-lane GLOBAL address (both-sides-or-neither rule).
//  - MFMA fragment semantics and C writeback bit-identical to round 8 -> absmax 0.0.

#define T_STEPS 2000
#define NIN_K   8192
#define NOUT_N  4096
#define MPAD    2048

typedef __attribute__((ext_vector_type(8))) _Float16 half8;  // 8 fp16 = 4 VGPRs
typedef __attribute__((ext_vector_type(4))) float f32x4;

#define GLL16(g, l)                                                              \
    __builtin_amdgcn_global_load_lds(                                            \
        (const __attribute__((address_space(1))) void*)(g),                      \
        (__attribute__((address_space(3))) void*)(l), 16, 0, 0)

// ---------------- decompose: fp32 -> (hi, lo*2^12) fp16 ----------------
__global__ __launch_bounds__(256) void split_f32(const float* __restrict__ src,
                                                 _Float16* __restrict__ hi,
                                                 _Float16* __restrict__ lo,
                                                 size_t n_valid) {
    const size_t i8 = (size_t)(blockIdx.x * 256u + threadIdx.x) * 8;
    float vv[8];
    if (i8 < n_valid) {
        float4 v0 = *(const float4*)(src + i8);
        float4 v1 = *(const float4*)(src + i8 + 4);
        vv[0] = v0.x; vv[1] = v0.y; vv[2] = v0.z; vv[3] = v0.w;
        vv[4] = v1.x; vv[5] = v1.y; vv[6] = v1.z; vv[7] = v1.w;
    } else {
#pragma unroll
        for (int j = 0; j < 8; ++j) vv[j] = 0.f;
    }
    half8 h8, l8;
#pragma unroll
    for (int j = 0; j < 8; ++j) {
        _Float16 h = (_Float16)vv[j];               // RN
        float r = __fsub_rn(vv[j], (float)h);       // exact
        h8[j] = h;
        l8[j] = (_Float16)(r * 4096.0f);            // exact shift + one RN
    }
    *(half8*)(hi + i8) = h8;
    *(half8*)(lo + i8) = l8;
}

// ---------------- split-fp16 MFMA GEMM: BK=32 dbuf, counted vmcnt, 2 blk/CU ----------------
__global__ __launch_bounds__(256, 2) void gemm_f16x2(const _Float16* __restrict__ A0,
                                                     const _Float16* __restrict__ A1,
                                                     const _Float16* __restrict__ B0,
                                                     const _Float16* __restrict__ B1,
                                                     float* __restrict__ C) {
    // 2 buffers x {A0,A1,B0,B1} x 128 rows x 32 halves (paired-row layout) = 64 KB
    __shared__ _Float16 lds[2][4][128 * 32];

    const int tid  = threadIdx.x;
    const int wave = tid >> 6;   // 0..3
    const int lane = tid & 63;
    const int bm = blockIdx.y * 128;
    const int bn = blockIdx.x * 128;
    const int wm = (wave >> 1) * 64;   // 0 or 64
    const int wn = (wave & 1) * 64;    // 0 or 64

    // ---- staging geometry: wave w covers rows w*32..w*32+31 of each array,
    //      two GLLs of 16 rows each. Paired-row lane mapping (see header).
    const int rch = 2 * (lane >> 3) + ((lane >> 2) & 1);   // row within 16-row chunk
    const int kh  = ((lane & 3) ^ ((lane >> 3) & 3)) * 8;  // true k-offset (halves)
    const int sr0 = wave * 32 + rch;
    const int sr1 = sr0 + 16;
    const _Float16* pa00 = A0 + (size_t)(bm + sr0) * NIN_K + kh;
    const _Float16* pa01 = A0 + (size_t)(bm + sr1) * NIN_K + kh;
    const _Float16* pa10 = A1 + (size_t)(bm + sr0) * NIN_K + kh;
    const _Float16* pa11 = A1 + (size_t)(bm + sr1) * NIN_K + kh;
    const _Float16* pb00 = B0 + (size_t)(bn + sr0) * NIN_K + kh;
    const _Float16* pb01 = B0 + (size_t)(bn + sr1) * NIN_K + kh;
    const _Float16* pb10 = B1 + (size_t)(bn + sr0) * NIN_K + kh;
    const _Float16* pb11 = B1 + (size_t)(bn + sr1) * NIN_K + kh;
    const int ldsOff0 = (wave * 32) * 32;       // halves; wave-uniform (HW adds lane*16B)
    const int ldsOff1 = (wave * 32 + 16) * 32;

    const int quad = lane >> 4;
    const int l16  = lane & 15;

    // fragment read offsets (loop-invariant): paired-row + XOR swizzle
    int offA[4], offB[4];
#pragma unroll
    for (int i = 0; i < 4; ++i) {
        const int row = wm + i * 16 + l16;
        offA[i] = (row >> 1) * 64 + (row & 1) * 32 + ((quad ^ ((row >> 1) & 3))) * 8;
    }
#pragma unroll
    for (int j = 0; j < 4; ++j) {
        const int row = wn + j * 16 + l16;
        offB[j] = (row >> 1) * 64 + (row & 1) * 32 + ((quad ^ ((row >> 1) & 3))) * 8;
    }

    f32x4 acc0[4][4], acc1[4][4];
#pragma unroll
    for (int i = 0; i < 4; ++i)
#pragma unroll
        for (int j = 0; j < 4; ++j) {
            acc0[i][j] = (f32x4){0.f, 0.f, 0.f, 0.f};
            acc1[i][j] = (f32x4){0.f, 0.f, 0.f, 0.f};
        }

#define STAGE(BUF)                                                               \
    {                                                                            \
        GLL16(pa00, &lds[BUF][0][ldsOff0]); GLL16(pa01, &lds[BUF][0][ldsOff1]);  \
        GLL16(pa10, &lds[BUF][1][ldsOff0]); GLL16(pa11, &lds[BUF][1][ldsOff1]);  \
        GLL16(pb00, &lds[BUF][2][ldsOff0]); GLL16(pb01, &lds[BUF][2][ldsOff1]);  \
        GLL16(pb10, &lds[BUF][3][ldsOff0]); GLL16(pb11, &lds[BUF][3][ldsOff1]);  \
        pa00 += 32; pa01 += 32; pa10 += 32; pa11 += 32;                          \
        pb00 += 32; pb01 += 32; pb10 += 32; pb11 += 32;                          \
    }

#define WAIT8  asm volatile("s_waitcnt vmcnt(8)" ::: "memory")
#define WAIT0  asm volatile("s_waitcnt vmcnt(0)" ::: "memory")
#define BARRIER                                                                  \
    {                                                                            \
        __builtin_amdgcn_s_barrier();                                            \
        __builtin_amdgcn_sched_barrier(0);                                       \
    }

#define COMPUTE(BUF)                                                             \
    {                                                                            \
        half8 b0f[4], b1f[4];                                                    \
        _Pragma("unroll") for (int j = 0; j < 4; ++j) {                          \
            b0f[j] = *(const half8*)&lds[BUF][2][offB[j]];                       \
            b1f[j] = *(const half8*)&lds[BUF][3][offB[j]];                       \
        }                                                                        \
        _Pragma("unroll") for (int i = 0; i < 4; ++i) {                          \
            const half8 a0f = *(const half8*)&lds[BUF][0][offA[i]];              \
            const half8 a1f = *(const half8*)&lds[BUF][1][offA[i]];              \
            _Pragma("unroll") for (int j = 0; j < 4; ++j) {                      \
                acc0[i][j] = __builtin_amdgcn_mfma_f32_16x16x32_f16(a0f, b0f[j], acc0[i][j], 0, 0, 0); \
                acc1[i][j] = __builtin_amdgcn_mfma_f32_16x16x32_f16(a0f, b1f[j], acc1[i][j], 0, 0, 0); \
                acc1[i][j] = __builtin_amdgcn_mfma_f32_16x16x32_f16(a1f, b0f[j], acc1[i][j], 0, 0, 0); \
            }                                                                    \
        }                                                                        \
    }

    // prologue: tile 0 -> buf0
    STAGE(0)

    // 256 K-tiles of 32. Loop pairs; prefetch distance 1 tile.
#pragma unroll 1
    for (int t = 0; t < 254; t += 2) {
        STAGE(1)              // tile t+1 -> buf1
        WAIT8;                // own tile-t GLLs retired (exactly 8 younger)
        BARRIER               // all waves' tile-t data resident
        COMPUTE(0)            // tile t
        BARRIER               // buf0 free for overwrite
        STAGE(0)              // tile t+2 -> buf0
        WAIT8;
        BARRIER
        COMPUTE(1)            // tile t+1
        BARRIER               // buf1 free for overwrite
    }
    // tail: tiles 254, 255
    STAGE(1)                  // tile 255 -> buf1
    WAIT8;
    BARRIER
    COMPUTE(0)                // tile 254
    WAIT0;                    // tile 255 GLLs retired
    BARRIER
    COMPUTE(1)                // tile 255

#undef STAGE
#undef WAIT8
#undef WAIT0
#undef BARRIER
#undef COMPUTE

    // C/D layout (m89-verified): col = lane&15, row = quad*4 + reg
    const float s = 1.0f / 4096.0f;
#pragma unroll
    for (int i = 0; i < 4; ++i)
#pragma unroll
        for (int j = 0; j < 4; ++j) {
            const int m = bm + wm + i * 16 + quad * 4;
            const int n = bn + wn + j * 16 + l16;
            float* cp = C + (size_t)m * NOUT_N + n;
#pragma unroll
            for (int r = 0; r < 4; ++r)
                cp[(size_t)r * NOUT_N] = __fmaf_rn(acc1[i][j][r], s, acc0[i][j][r]);
        }
}

// ---------------- fallback fp32 GEMM (round-1 proven; reads RAW x/w) ----------------
#define BM 64
#define BN 64
#define BK 16
#define PAD 4
__global__ __launch_bounds__(256) void gemm_bt(const float* __restrict__ A,
                                               const float* __restrict__ B,
                                               float* __restrict__ C,
                                               int M, int N, int K) {
    __shared__ float As[BK][BM + PAD];
    __shared__ float Bs[BK][BN + PAD];
    const int bm = blockIdx.y * BM, bn = blockIdx.x * BN;
    const int tid = threadIdx.x;
    const int tx = tid & 15, ty = tid >> 4;
    const int lrow = tid >> 2, lk = (tid & 3) * 4;
    float acc[4][4];
#pragma unroll
    for (int i = 0; i < 4; ++i)
#pragma unroll
        for (int j = 0; j < 4; ++j) acc[i][j] = 0.0f;
    for (int k0 = 0; k0 < K; k0 += BK) {
        const int am = bm + lrow;
        float4 av = (am < M) ? *(const float4*)(A + (size_t)am * K + k0 + lk)
                             : make_float4(0.f, 0.f, 0.f, 0.f);
        As[lk + 0][lrow] = av.x; As[lk + 1][lrow] = av.y;
        As[lk + 2][lrow] = av.z; As[lk + 3][lrow] = av.w;
        float4 bv = *(const float4*)(B + (size_t)(bn + lrow) * K + k0 + lk);
        Bs[lk + 0][lrow] = bv.x; Bs[lk + 1][lrow] = bv.y;
        Bs[lk + 2][lrow] = bv.z; Bs[lk + 3][lrow] = bv.w;
        __syncthreads();
#pragma unroll
        for (int k = 0; k < BK; ++k) {
            float a[4], b[4];
#pragma unroll
            for (int i = 0; i < 4; ++i) a[i] = As[k][ty * 4 + i];
#pragma unroll
            for (int j = 0; j < 4; ++j) b[j] = Bs[k][tx * 4 + j];
#pragma unroll
            for (int i = 0; i < 4; ++i)
#pragma unroll
                for (int j = 0; j < 4; ++j) acc[i][j] += a[i] * b[j];
        }
        __syncthreads();
    }
#pragma unroll
    for (int i = 0; i < 4; ++i) {
        const int m = bm + ty * 4 + i;
        if (m < M) {
            float* cp = C + (size_t)m * N + bn + tx * 4;
#pragma unroll
            for (int j = 0; j < 4; ++j) cp[j] = acc[i][j];
        }
    }
}

// zero-fill pad rows of lif (fallback path only; main path writes them via GEMM)
__global__ void zero_rows(float* __restrict__ p, size_t n) {
    const size_t i = (size_t)blockIdx.x * 256 + threadIdx.x;
    if (i < n) p[i] = 0.0f;
}

// ---------------- sequential LIF scan (round 8: all-asm register ring; kept) ----------------
__global__ __launch_bounds__(64) void lif_scan(const float* __restrict__ inp,
                                               const float* __restrict__ v_th_p,
                                               const float* __restrict__ v_rest_p,
                                               const float* __restrict__ v_reset_p,
                                               const float* __restrict__ t_ref_p,
                                               const float* __restrict__ tau_p,
                                               float* __restrict__ out) {
    const int lane = threadIdx.x;  // 0..63, one wave
    const int j = blockIdx.x * 64 + lane;

    const float vth = v_th_p[j], vrest = v_rest_p[j], vres = v_reset_p[j];
    const float tref = t_ref_p[j];
    const float cleak = __fmul_rn(0.001f, tau_p[j]);
    float v = vrest, refrac = 0.0f;
    out[j] = 0.0f;  // row 0 stays zero

    const float* plv = inp + (size_t)1 * NOUT_N + j;  // next row to LOAD (starts at row 1)
    float* pst = out + (size_t)1 * NOUT_N + j;        // next row to STORE (starts at t=1)

    float p00, p01, p02, p03, p04, p05, p06, p07, p08, p09, p10, p11, p12, p13, p14, p15;
    float p16, p17, p18, p19, p20, p21, p22, p23, p24, p25, p26, p27, p28, p29, p30, p31;

#define LDP(PD)                                                                   \
    asm volatile("global_load_dword %0, %1, off" : "=v"(PD) : "v"(plv) : "memory"); \
    plv += NOUT_N;

#define STEPA(PD, WSTR)                                                           \
    {                                                                             \
        asm volatile(WSTR : "+v"(PD)::"memory");                                  \
        const float in = PD;                                                      \
        const float dd = __fmul_rn(cleak, __fsub_rn(v, vrest));                   \
        v = __fsub_rn(v, dd);                                                     \
        v = (refrac == 0.0f) ? __fadd_rn(v, in) : v;                              \
        refrac = (refrac > 0.0f) ? (refrac - 0.001f) : 0.0f;                      \
        const bool s = (__fsub_rn(v, vth) >= 0.0f);                               \
        const float spk = s ? 1.0f : 0.0f;                                        \
        asm volatile("global_store_dword %0, %1, off" ::"v"(pst), "v"(spk)        \
                     : "memory");                                                 \
        pst += NOUT_N;                                                            \
        asm volatile("global_load_dword %0, %1, off" : "=v"(PD) : "v"(plv)        \
                     : "memory");                                                 \
        plv += NOUT_N;                                                            \
        refrac = s ? tref : refrac;                                               \
        v = s ? vres : v;                                                         \
    }

#define GROUP32(WSTR)                                                             \
    STEPA(p00, WSTR) STEPA(p01, WSTR) STEPA(p02, WSTR) STEPA(p03, WSTR)           \
    STEPA(p04, WSTR) STEPA(p05, WSTR) STEPA(p06, WSTR) STEPA(p07, WSTR)           \
    STEPA(p08, WSTR) STEPA(p09, WSTR) STEPA(p10, WSTR) STEPA(p11, WSTR)           \
    STEPA(p12, WSTR) STEPA(p13, WSTR) STEPA(p14, WSTR) STEPA(p15, WSTR)           \
    STEPA(p16, WSTR) STEPA(p17, WSTR) STEPA(p18, WSTR) STEPA(p19, WSTR)           \
    STEPA(p20, WSTR) STEPA(p21, WSTR) STEPA(p22, WSTR) STEPA(p23, WSTR)           \
    STEPA(p24, WSTR) STEPA(p25, WSTR) STEPA(p26, WSTR) STEPA(p27, WSTR)           \
    STEPA(p28, WSTR) STEPA(p29, WSTR) STEPA(p30, WSTR) STEPA(p31, WSTR)

#define TAILSTEP(PD)                                                              \
    {                                                                             \
        const float in = PD;                                                      \
        const float dd = __fmul_rn(cleak, __fsub_rn(v, vrest));                   \
        v = __fsub_rn(v, dd);                                                     \
        v = (refrac == 0.0f) ? __fadd_rn(v, in) : v;                              \
        refrac = (refrac > 0.0f) ? (refrac - 0.001f) : 0.0f;                      \
        const bool s = (__fsub_rn(v, vth) >= 0.0f);                               \
        *pst = s ? 1.0f : 0.0f;                                                   \
        pst += NOUT_N;                                                            \
        refrac = s ? tref : refrac;                                               \
        v = s ? vres : v;                                                         \
    }

    // prologue: rows 1..32 in flight
    LDP(p00) LDP(p01) LDP(p02) LDP(p03) LDP(p04) LDP(p05) LDP(p06) LDP(p07)
    LDP(p08) LDP(p09) LDP(p10) LDP(p11) LDP(p12) LDP(p13) LDP(p14) LDP(p15)
    LDP(p16) LDP(p17) LDP(p18) LDP(p19) LDP(p20) LDP(p21) LDP(p22) LDP(p23)
    LDP(p24) LDP(p25) LDP(p26) LDP(p27) LDP(p28) LDP(p29) LDP(p30) LDP(p31)

    // group 0: t = 1..32 (prefetch rows 33..64); younger(load row 1+d) = 31+d
    GROUP32("s_waitcnt vmcnt(31)")

    // steady: 61 groups, t = 33..1984 (prefetch up to row 2016); younger = 62
#pragma unroll 1
    for (int g = 1; g < 62; ++g) {
        GROUP32("s_waitcnt vmcnt(62)")
    }

    // drain everything (also flushes all asm stores before endpgm)
    asm volatile("s_waitcnt vmcnt(0)" ::: "memory");
    __builtin_amdgcn_sched_barrier(0);  // rule #18: no reg-use hoisting above the wait

    // tail: t = 1985..1999 from p00..p14 (loaded as rows 1985..1999)
    TAILSTEP(p00) TAILSTEP(p01) TAILSTEP(p02) TAILSTEP(p03) TAILSTEP(p04)
    TAILSTEP(p05) TAILSTEP(p06) TAILSTEP(p07) TAILSTEP(p08) TAILSTEP(p09)
    TAILSTEP(p10) TAILSTEP(p11) TAILSTEP(p12) TAILSTEP(p13) TAILSTEP(p14)

#undef LDP
#undef STEPA
#undef GROUP32
#undef TAILSTEP
}

extern "C" void kernel_launch(void* const* d_in, const int* in_sizes, int n_in,
                              void* d_out, int out_size, void* d_ws, size_t ws_size,
                              hipStream_t stream) {
    const float* x       = (const float*)d_in[0];
    const float* w       = (const float*)d_in[1];
    const float* v_th    = (const float*)d_in[2];
    const float* v_rest  = (const float*)d_in[3];
    const float* v_reset = (const float*)d_in[4];
    const float* t_ref   = (const float*)d_in[5];
    const float* tau     = (const float*)d_in[6];
    float* out = (float*)d_out;

    const size_t LIF_B = (size_t)MPAD * NOUT_N * 4;        //  32 MiB
    const size_t XS_B  = (size_t)MPAD * NIN_K * 2;         //  32 MiB each
    const size_t WS_B  = (size_t)NOUT_N * NIN_K * 2;       //  64 MiB each
    const size_t NEED  = LIF_B + 2 * XS_B + 2 * WS_B;      // 224 MiB

    char* ws = (char*)d_ws;
    float* lif = (float*)ws;

    if (ws_size >= NEED) {
        _Float16* x0 = (_Float16*)(ws + LIF_B);
        _Float16* x1 = (_Float16*)(ws + LIF_B + XS_B);
        _Float16* w0 = (_Float16*)(ws + LIF_B + 2 * XS_B);
        _Float16* w1 = (_Float16*)(ws + LIF_B + 2 * XS_B + WS_B);

        const size_t nx = (size_t)MPAD * NIN_K;
        split_f32<<<nx / 8 / 256, 256, 0, stream>>>(x, x0, x1,
                                                    (size_t)T_STEPS * NIN_K);
        const size_t nw = (size_t)NOUT_N * NIN_K;
        split_f32<<<nw / 8 / 256, 256, 0, stream>>>(w, w0, w1, nw);

        dim3 g(NOUT_N / 128, MPAD / 128);
        gemm_f16x2<<<g, 256, 0, stream>>>(x0, x1, w0, w1, lif);
    } else {
        dim3 g(NOUT_N / BN, (T_STEPS + BM - 1) / BM);
        gemm_bt<<<g, 256, 0, stream>>>(x, w, lif, T_STEPS, NOUT_N, NIN_K);
        const size_t padn = (size_t)(MPAD - T_STEPS) * NOUT_N;
        zero_rows<<<(padn + 255) / 256, 256, 0, stream>>>(lif + (size_t)T_STEPS * NOUT_N, padn);
    }

    lif_scan<<<NOUT_N / 64, 64, 0, stream>>>(lif, v_th, v_rest, v_reset, t_ref, tau, out);
}

// Round 5
// 702.821 us; speedup vs baseline: 1.1159x; 1.1159x over previous
//
#include <hip/hip_runtime.h>
#include <hip/hip_bf16.h>

// LIF layer: lif_input[T,NOUT] = x[T,NIN] @ W[NOUT,NIN]^T (fp32), then sequential scan.
// fp32 GEMM on matrix pipe via fp16 2-way SCALED split, 3 MFMA products:
//   a = a0 + a1*2^-12 (a1 pre-scaled by 2^12: dodges fp16 subnormal flush)
//   C = acc0(A0B0) + 2^-12 * acc1(A0B1 + A1B0); error ~2^-24|ab| (fp32-noise level).
// Round-11 (GEMM only; splits + round-8 asm-ring scan kept):
//  - R9 falsified 64x32 wave-tiles (LDS 512B/MFMA cap) and 1 blk/CU (no filler).
//  - R10 falsified BK=32: 64B-per-row K-tiles = half an L2 line; line must
//    survive a full tile-phase in 4MB/XCD L2 to serve the other half -> FETCH
//    tripled (460MB -> 1.43GB), kernel went L2-miss-BW-bound.
//  - Constraints: BK=64 (full 128B lines), 64x64 wave tiles, 2 blk/CU ->
//    LDS <= 80KB -> no full double buffer. Pipeline INSIDE the K-step instead:
//    product structure splits naturally. Issue A0/B0 GLLs (8) then A1/B1 (8);
//    vmcnt(8)+s_barrier (half drain, partly covered by issuing 2nd group);
//    32 acc0 MFMAs (A0B0); vmcnt(0)+s_barrier (A1/B1 latency hidden under
//    phase-1 MFMA); 64 correction MFMAs; barrier; next stage. Raw-barrier +
//    counted-wait pattern correctness proven in R9/R10 (absmax 0.0).
//  - Accumulation order per acc element unchanged -> bit-identical output.

#define T_STEPS 2000
#define NIN_K   8192
#define NOUT_N  4096
#define MPAD    2048

typedef __attribute__((ext_vector_type(8))) _Float16 half8;  // 8 fp16 = 4 VGPRs
typedef __attribute__((ext_vector_type(4))) float f32x4;

#define GLL16(g, l)                                                              \
    __builtin_amdgcn_global_load_lds(                                            \
        (const __attribute__((address_space(1))) void*)(g),                      \
        (__attribute__((address_space(3))) void*)(l), 16, 0, 0)

// ---------------- decompose: fp32 -> (hi, lo*2^12) fp16 ----------------
__global__ __launch_bounds__(256) void split_f32(const float* __restrict__ src,
                                                 _Float16* __restrict__ hi,
                                                 _Float16* __restrict__ lo,
                                                 size_t n_valid) {
    const size_t i8 = (size_t)(blockIdx.x * 256u + threadIdx.x) * 8;
    float vv[8];
    if (i8 < n_valid) {
        float4 v0 = *(const float4*)(src + i8);
        float4 v1 = *(const float4*)(src + i8 + 4);
        vv[0] = v0.x; vv[1] = v0.y; vv[2] = v0.z; vv[3] = v0.w;
        vv[4] = v1.x; vv[5] = v1.y; vv[6] = v1.z; vv[7] = v1.w;
    } else {
#pragma unroll
        for (int j = 0; j < 8; ++j) vv[j] = 0.f;
    }
    half8 h8, l8;
#pragma unroll
    for (int j = 0; j < 8; ++j) {
        _Float16 h = (_Float16)vv[j];               // RN
        float r = __fsub_rn(vv[j], (float)h);       // exact
        h8[j] = h;
        l8[j] = (_Float16)(r * 4096.0f);            // exact shift + one RN
    }
    *(half8*)(hi + i8) = h8;
    *(half8*)(lo + i8) = l8;
}

// ---------------- split-fp16 MFMA GEMM, BK=64, intra-K-step phase split ----------------
// Block tile 128x128, 4 waves of 64x64 (4x4 frags of 16x16x32), 128 K-iters.
// LDS row layout: [row][64 halves] = 128 B/row; 16B slot s of row r holds TRUE
// k-group s^(r&7) (stage-side per-lane global-address swizzle). Fragment for
// (ks,quad) reads slot (ks*4+quad)^(r&7) -> 8 distinct banks, 2-way, free.
__global__ __launch_bounds__(256, 2) void gemm_f16x2(const _Float16* __restrict__ A0,
                                                     const _Float16* __restrict__ A1,
                                                     const _Float16* __restrict__ B0,
                                                     const _Float16* __restrict__ B1,
                                                     float* __restrict__ C) {
    __shared__ _Float16 lds[4][128 * 64];  // A0,A1,B0,B1: 16 KB each = 64 KB

    const int tid  = threadIdx.x;
    const int wave = tid >> 6;
    const int lane = tid & 63;
    const int bm = blockIdx.y * 128;
    const int bn = blockIdx.x * 128;
    const int wm = (wave >> 1) * 64;
    const int wn = (wave & 1) * 64;

    // Staging: per c-chunk, thread covers row c*32 + (tid>>3), 16B slot tid&7.
    // Global k-group swizzled: (tid&7) ^ ((tid>>3)&7)  [(tid>>3)&7 == row&7]
    const int srow = tid >> 3;                       // 0..31
    const int skswz = ((tid & 7) ^ (srow & 7)) * 8;  // halves

    f32x4 acc0[4][4], acc1[4][4];
#pragma unroll
    for (int i = 0; i < 4; ++i)
#pragma unroll
        for (int j = 0; j < 4; ++j) {
            acc0[i][j] = (f32x4){0.f, 0.f, 0.f, 0.f};
            acc1[i][j] = (f32x4){0.f, 0.f, 0.f, 0.f};
        }

    const int quad = lane >> 4;
    const int l16  = lane & 15;

#define BARRIER                                                                  \
    {                                                                            \
        __builtin_amdgcn_s_barrier();                                            \
        __builtin_amdgcn_sched_barrier(0);                                       \
    }

#pragma unroll 1
    for (int k0 = 0; k0 < NIN_K; k0 += 64) {
        // ---- STAGE: group 1 = A0,B0 (8 GLLs), group 2 = A1,B1 (8 GLLs) ----
#pragma unroll
        for (int c = 0; c < 4; ++c) {
            const size_t ga = (size_t)(bm + c * 32 + srow) * NIN_K + k0 + skswz;
            const size_t gb = (size_t)(bn + c * 32 + srow) * NIN_K + k0 + skswz;
            const int base = (c * 32 + wave * 8) * 64;  // wave-uniform (HW adds lane*16B)
            GLL16(A0 + ga, &lds[0][base]);
            GLL16(B0 + gb, &lds[2][base]);
        }
#pragma unroll
        for (int c = 0; c < 4; ++c) {
            const size_t ga = (size_t)(bm + c * 32 + srow) * NIN_K + k0 + skswz;
            const size_t gb = (size_t)(bn + c * 32 + srow) * NIN_K + k0 + skswz;
            const int base = (c * 32 + wave * 8) * 64;
            GLL16(A1 + ga, &lds[1][base]);
            GLL16(B1 + gb, &lds[3][base]);
        }

        // ---- phase 1: A0/B0 resident (own 8 oldest retired; barrier syncs waves) ----
        asm volatile("s_waitcnt vmcnt(8)" ::: "memory");
        BARRIER
#pragma unroll
        for (int ks = 0; ks < 2; ++ks) {
            half8 b0f[4];
#pragma unroll
            for (int j = 0; j < 4; ++j) {
                const int row = wn + j * 16 + l16;
                b0f[j] = *(const half8*)&lds[2][row * 64 + ((ks * 4 + quad) ^ (row & 7)) * 8];
            }
#pragma unroll
            for (int i = 0; i < 4; ++i) {
                const int row = wm + i * 16 + l16;
                const half8 a0f = *(const half8*)&lds[0][row * 64 + ((ks * 4 + quad) ^ (row & 7)) * 8];
#pragma unroll
                for (int j = 0; j < 4; ++j)
                    acc0[i][j] = __builtin_amdgcn_mfma_f32_16x16x32_f16(a0f, b0f[j], acc0[i][j], 0, 0, 0);
            }
        }

        // ---- phase 2: A1/B1 resident (latency hidden under phase-1 MFMAs) ----
        asm volatile("s_waitcnt vmcnt(0)" ::: "memory");
        BARRIER
#pragma unroll
        for (int ks = 0; ks < 2; ++ks) {
            half8 b0f[4], b1f[4];
#pragma unroll
            for (int j = 0; j < 4; ++j) {
                const int row = wn + j * 16 + l16;
                const int off = row * 64 + ((ks * 4 + quad) ^ (row & 7)) * 8;
                b0f[j] = *(const half8*)&lds[2][off];
                b1f[j] = *(const half8*)&lds[3][off];
            }
#pragma unroll
            for (int i = 0; i < 4; ++i) {
                const int row = wm + i * 16 + l16;
                const int off = row * 64 + ((ks * 4 + quad) ^ (row & 7)) * 8;
                const half8 a0f = *(const half8*)&lds[0][off];
                const half8 a1f = *(const half8*)&lds[1][off];
#pragma unroll
                for (int j = 0; j < 4; ++j) {
                    acc1[i][j] = __builtin_amdgcn_mfma_f32_16x16x32_f16(a0f, b1f[j], acc1[i][j], 0, 0, 0);
                    acc1[i][j] = __builtin_amdgcn_mfma_f32_16x16x32_f16(a1f, b0f[j], acc1[i][j], 0, 0, 0);
                }
            }
        }

        // ---- all waves done reading before next STAGE overwrites ----
        BARRIER
    }
#undef BARRIER

    // C/D layout (m89-verified): col = lane&15, row = quad*4 + reg
    const float s = 1.0f / 4096.0f;
#pragma unroll
    for (int i = 0; i < 4; ++i)
#pragma unroll
        for (int j = 0; j < 4; ++j) {
            const int m = bm + wm + i * 16 + quad * 4;
            const int n = bn + wn + j * 16 + l16;
            float* cp = C + (size_t)m * NOUT_N + n;
#pragma unroll
            for (int r = 0; r < 4; ++r)
                cp[(size_t)r * NOUT_N] = __fmaf_rn(acc1[i][j][r], s, acc0[i][j][r]);
        }
}

// ---------------- fallback fp32 GEMM (round-1 proven; reads RAW x/w) ----------------
#define BM 64
#define BN 64
#define BK 16
#define PAD 4
__global__ __launch_bounds__(256) void gemm_bt(const float* __restrict__ A,
                                               const float* __restrict__ B,
                                               float* __restrict__ C,
                                               int M, int N, int K) {
    __shared__ float As[BK][BM + PAD];
    __shared__ float Bs[BK][BN + PAD];
    const int bm = blockIdx.y * BM, bn = blockIdx.x * BN;
    const int tid = threadIdx.x;
    const int tx = tid & 15, ty = tid >> 4;
    const int lrow = tid >> 2, lk = (tid & 3) * 4;
    float acc[4][4];
#pragma unroll
    for (int i = 0; i < 4; ++i)
#pragma unroll
        for (int j = 0; j < 4; ++j) acc[i][j] = 0.0f;
    for (int k0 = 0; k0 < K; k0 += BK) {
        const int am = bm + lrow;
        float4 av = (am < M) ? *(const float4*)(A + (size_t)am * K + k0 + lk)
                             : make_float4(0.f, 0.f, 0.f, 0.f);
        As[lk + 0][lrow] = av.x; As[lk + 1][lrow] = av.y;
        As[lk + 2][lrow] = av.z; As[lk + 3][lrow] = av.w;
        float4 bv = *(const float4*)(B + (size_t)(bn + lrow) * K + k0 + lk);
        Bs[lk + 0][lrow] = bv.x; Bs[lk + 1][lrow] = bv.y;
        Bs[lk + 2][lrow] = bv.z; Bs[lk + 3][lrow] = bv.w;
        __syncthreads();
#pragma unroll
        for (int k = 0; k < BK; ++k) {
            float a[4], b[4];
#pragma unroll
            for (int i = 0; i < 4; ++i) a[i] = As[k][ty * 4 + i];
#pragma unroll
            for (int j = 0; j < 4; ++j) b[j] = Bs[k][tx * 4 + j];
#pragma unroll
            for (int i = 0; i < 4; ++i)
#pragma unroll
                for (int j = 0; j < 4; ++j) acc[i][j] += a[i] * b[j];
        }
        __syncthreads();
    }
#pragma unroll
    for (int i = 0; i < 4; ++i) {
        const int m = bm + ty * 4 + i;
        if (m < M) {
            float* cp = C + (size_t)m * N + bn + tx * 4;
#pragma unroll
            for (int j = 0; j < 4; ++j) cp[j] = acc[i][j];
        }
    }
}

// zero-fill pad rows of lif (fallback path only; main path writes them via GEMM)
__global__ void zero_rows(float* __restrict__ p, size_t n) {
    const size_t i = (size_t)blockIdx.x * 256 + threadIdx.x;
    if (i < n) p[i] = 0.0f;
}

// ---------------- sequential LIF scan (round 8: all-asm register ring; kept) ----------------
__global__ __launch_bounds__(64) void lif_scan(const float* __restrict__ inp,
                                               const float* __restrict__ v_th_p,
                                               const float* __restrict__ v_rest_p,
                                               const float* __restrict__ v_reset_p,
                                               const float* __restrict__ t_ref_p,
                                               const float* __restrict__ tau_p,
                                               float* __restrict__ out) {
    const int lane = threadIdx.x;  // 0..63, one wave
    const int j = blockIdx.x * 64 + lane;

    const float vth = v_th_p[j], vrest = v_rest_p[j], vres = v_reset_p[j];
    const float tref = t_ref_p[j];
    const float cleak = __fmul_rn(0.001f, tau_p[j]);
    float v = vrest, refrac = 0.0f;
    out[j] = 0.0f;  // row 0 stays zero

    const float* plv = inp + (size_t)1 * NOUT_N + j;  // next row to LOAD (starts at row 1)
    float* pst = out + (size_t)1 * NOUT_N + j;        // next row to STORE (starts at t=1)

    float p00, p01, p02, p03, p04, p05, p06, p07, p08, p09, p10, p11, p12, p13, p14, p15;
    float p16, p17, p18, p19, p20, p21, p22, p23, p24, p25, p26, p27, p28, p29, p30, p31;

#define LDP(PD)                                                                   \
    asm volatile("global_load_dword %0, %1, off" : "=v"(PD) : "v"(plv) : "memory"); \
    plv += NOUT_N;

#define STEPA(PD, WSTR)                                                           \
    {                                                                             \
        asm volatile(WSTR : "+v"(PD)::"memory");                                  \
        const float in = PD;                                                      \
        const float dd = __fmul_rn(cleak, __fsub_rn(v, vrest));                   \
        v = __fsub_rn(v, dd);                                                     \
        v = (refrac == 0.0f) ? __fadd_rn(v, in) : v;                              \
        refrac = (refrac > 0.0f) ? (refrac - 0.001f) : 0.0f;                      \
        const bool s = (__fsub_rn(v, vth) >= 0.0f);                               \
        const float spk = s ? 1.0f : 0.0f;                                        \
        asm volatile("global_store_dword %0, %1, off" ::"v"(pst), "v"(spk)        \
                     : "memory");                                                 \
        pst += NOUT_N;                                                            \
        asm volatile("global_load_dword %0, %1, off" : "=v"(PD) : "v"(plv)        \
                     : "memory");                                                 \
        plv += NOUT_N;                                                            \
        refrac = s ? tref : refrac;                                               \
        v = s ? vres : v;                                                         \
    }

#define GROUP32(WSTR)                                                             \
    STEPA(p00, WSTR) STEPA(p01, WSTR) STEPA(p02, WSTR) STEPA(p03, WSTR)           \
    STEPA(p04, WSTR) STEPA(p05, WSTR) STEPA(p06, WSTR) STEPA(p07, WSTR)           \
    STEPA(p08, WSTR) STEPA(p09, WSTR) STEPA(p10, WSTR) STEPA(p11, WSTR)           \
    STEPA(p12, WSTR) STEPA(p13, WSTR) STEPA(p14, WSTR) STEPA(p15, WSTR)           \
    STEPA(p16, WSTR) STEPA(p17, WSTR) STEPA(p18, WSTR) STEPA(p19, WSTR)           \
    STEPA(p20, WSTR) STEPA(p21, WSTR) STEPA(p22, WSTR) STEPA(p23, WSTR)           \
    STEPA(p24, WSTR) STEPA(p25, WSTR) STEPA(p26, WSTR) STEPA(p27, WSTR)           \
    STEPA(p28, WSTR) STEPA(p29, WSTR) STEPA(p30, WSTR) STEPA(p31, WSTR)

#define TAILSTEP(PD)                                                              \
    {                                                                             \
        const float in = PD;                                                      \
        const float dd = __fmul_rn(cleak, __fsub_rn(v, vrest));                   \
        v = __fsub_rn(v, dd);                                                     \
        v = (refrac == 0.0f) ? __fadd_rn(v, in) : v;                              \
        refrac = (refrac > 0.0f) ? (refrac - 0.001f) : 0.0f;                      \
        const bool s = (__fsub_rn(v, vth) >= 0.0f);                               \
        *pst = s ? 1.0f : 0.0f;                                                   \
        pst += NOUT_N;                                                            \
        refrac = s ? tref : refrac;                                               \
        v = s ? vres : v;                                                         \
    }

    // prologue: rows 1..32 in flight
    LDP(p00) LDP(p01) LDP(p02) LDP(p03) LDP(p04) LDP(p05) LDP(p06) LDP(p07)
    LDP(p08) LDP(p09) LDP(p10) LDP(p11) LDP(p12) LDP(p13) LDP(p14) LDP(p15)
    LDP(p16) LDP(p17) LDP(p18) LDP(p19) LDP(p20) LDP(p21) LDP(p22) LDP(p23)
    LDP(p24) LDP(p25) LDP(p26) LDP(p27) LDP(p28) LDP(p29) LDP(p30) LDP(p31)

    // group 0: t = 1..32 (prefetch rows 33..64); younger(load row 1+d) = 31+d
    GROUP32("s_waitcnt vmcnt(31)")

    // steady: 61 groups, t = 33..1984 (prefetch up to row 2016); younger = 62
#pragma unroll 1
    for (int g = 1; g < 62; ++g) {
        GROUP32("s_waitcnt vmcnt(62)")
    }

    // drain everything (also flushes all asm stores before endpgm)
    asm volatile("s_waitcnt vmcnt(0)" ::: "memory");
    __builtin_amdgcn_sched_barrier(0);  // rule #18: no reg-use hoisting above the wait

    // tail: t = 1985..1999 from p00..p14 (loaded as rows 1985..1999)
    TAILSTEP(p00) TAILSTEP(p01) TAILSTEP(p02) TAILSTEP(p03) TAILSTEP(p04)
    TAILSTEP(p05) TAILSTEP(p06) TAILSTEP(p07) TAILSTEP(p08) TAILSTEP(p09)
    TAILSTEP(p10) TAILSTEP(p11) TAILSTEP(p12) TAILSTEP(p13) TAILSTEP(p14)

#undef LDP
#undef STEPA
#undef GROUP32
#undef TAILSTEP
}

extern "C" void kernel_launch(void* const* d_in, const int* in_sizes, int n_in,
                              void* d_out, int out_size, void* d_ws, size_t ws_size,
                              hipStream_t stream) {
    const float* x       = (const float*)d_in[0];
    const float* w       = (const float*)d_in[1];
    const float* v_th    = (const float*)d_in[2];
    const float* v_rest  = (const float*)d_in[3];
    const float* v_reset = (const float*)d_in[4];
    const float* t_ref   = (const float*)d_in[5];
    const float* tau     = (const float*)d_in[6];
    float* out = (float*)d_out;

    const size_t LIF_B = (size_t)MPAD * NOUT_N * 4;        //  32 MiB
    const size_t XS_B  = (size_t)MPAD * NIN_K * 2;         //  32 MiB each
    const size_t WS_B  = (size_t)NOUT_N * NIN_K * 2;       //  64 MiB each
    const size_t NEED  = LIF_B + 2 * XS_B + 2 * WS_B;      // 224 MiB

    char* ws = (char*)d_ws;
    float* lif = (float*)ws;

    if (ws_size >= NEED) {
        _Float16* x0 = (_Float16*)(ws + LIF_B);
        _Float16* x1 = (_Float16*)(ws + LIF_B + XS_B);
        _Float16* w0 = (_Float16*)(ws + LIF_B + 2 * XS_B);
        _Float16* w1 = (_Float16*)(ws + LIF_B + 2 * XS_B + WS_B);

        const size_t nx = (size_t)MPAD * NIN_K;
        split_f32<<<nx / 8 / 256, 256, 0, stream>>>(x, x0, x1,
                                                    (size_t)T_STEPS * NIN_K);
        const size_t nw = (size_t)NOUT_N * NIN_K;
        split_f32<<<nw / 8 / 256, 256, 0, stream>>>(w, w0, w1, nw);

        dim3 g(NOUT_N / 128, MPAD / 128);
        gemm_f16x2<<<g, 256, 0, stream>>>(x0, x1, w0, w1, lif);
    } else {
        dim3 g(NOUT_N / BN, (T_STEPS + BM - 1) / BM);
        gemm_bt<<<g, 256, 0, stream>>>(x, w, lif, T_STEPS, NOUT_N, NIN_K);
        const size_t padn = (size_t)(MPAD - T_STEPS) * NOUT_N;
        zero_rows<<<(padn + 255) / 256, 256, 0, stream>>>(lif + (size_t)T_STEPS * NOUT_N, padn);
    }

    lif_scan<<<NOUT_N / 64, 64, 0, stream>>>(lif, v_th, v_rest, v_reset, t_ref, tau, out);
}